// Round 2
// baseline (646.886 us; speedup 1.0000x reference)
//
#include <hip/hip_runtime.h>
#include <math.h>

#define TT 2048
#define W 10

// ============== Kernel 1: returns + running vol (per-row scan) ==============
__global__ __launch_bounds__(256) void prep_kernel(const float* __restrict__ F,
                                                   float* __restrict__ ret,
                                                   float* __restrict__ vol) {
  __shared__ float sAbs[TT];
  __shared__ float sPart[256];
  const int b = blockIdx.x, tid = threadIdx.x;
  const float* fb = F + (size_t)b * TT * 5;
#pragma unroll
  for (int u = 0; u < 8; ++u) {
    int t = u * 256 + tid;
    float rv = 0.f;
    if (t > 0) rv = fb[t * 5] - fb[(t - 1) * 5];
    ret[b * TT + t] = rv;
    sAbs[t] = fabsf(rv);
  }
  __syncthreads();
  float loc[8];
  float run = 0.f;
#pragma unroll
  for (int u = 0; u < 8; ++u) { run += sAbs[tid * 8 + u]; loc[u] = run; }
  sPart[tid] = run;
  __syncthreads();
  for (int off = 1; off < 256; off <<= 1) {
    float v = (tid >= off) ? sPart[tid - off] : 0.f;
    __syncthreads();
    sPart[tid] += v;
    __syncthreads();
  }
  float excl = sPart[tid] - run;
#pragma unroll
  for (int u = 0; u < 8; ++u) {
    int t = tid * 8 + u;
    vol[b * TT + t] = (excl + loc[u]) / ((float)(t + 1) + 1e-8f);
  }
}

// ============== Kernel 2: H MLP + regime gate softmax ==============
__global__ __launch_bounds__(256) void gate_kernel(
    const float* __restrict__ ret, const float* __restrict__ vol,
    const float* __restrict__ hw1, const float* __restrict__ hb1,
    const float* __restrict__ hw2, const float* __restrict__ hb2,
    const float* __restrict__ hw3, const float* __restrict__ hb3,
    const float* __restrict__ gw1, const float* __restrict__ gb1,
    const float* __restrict__ gw2, const float* __restrict__ gb2,
    float* __restrict__ gate) {
  const int pos = blockIdx.x * 256 + threadIdx.x;
  const int t = pos & (TT - 1);
  const int start = (t >= W) ? (t - W) : 0;
  const float* rp = ret + (pos - t) + start;  // pos - t == b*TT
  float r[W];
#pragma unroll
  for (int u = 0; u < W; ++u) r[u] = rp[u];
  float h1v[32];
#pragma unroll
  for (int j = 0; j < 32; ++j) {
    float a = hb1[j];
#pragma unroll
    for (int u = 0; u < W; ++u) a = fmaf(r[u], hw1[u * 32 + j], a);
    h1v[j] = fmaxf(a, 0.f);
  }
  float hs = hb3[0];
#pragma unroll
  for (int j = 0; j < 32; ++j) {
    float a = hb2[j];
#pragma unroll
    for (int u = 0; u < 32; ++u) a = fmaf(h1v[u], hw2[u * 32 + j], a);
    hs = fmaf(fmaxf(a, 0.f), hw3[j], hs);
  }
  const float H = 0.5f / (1.f + expf(-hs));
  const float vv = vol[pos];
  float l0 = gb2[0], l1 = gb2[1], l2 = gb2[2], l3 = gb2[3];
#pragma unroll
  for (int j = 0; j < 32; ++j) {
    float z = fmaxf(fmaf(H, gw1[j], fmaf(vv, gw1[32 + j], gb1[j])), 0.f);
    l0 = fmaf(z, gw2[j * 4 + 0], l0);
    l1 = fmaf(z, gw2[j * 4 + 1], l1);
    l2 = fmaf(z, gw2[j * 4 + 2], l2);
    l3 = fmaf(z, gw2[j * 4 + 3], l3);
  }
  float m = fmaxf(fmaxf(l0, l1), fmaxf(l2, l3));
  float e0 = expf(l0 - m), e1 = expf(l1 - m), e2 = expf(l2 - m), e3 = expf(l3 - m);
  float inv = 1.f / (e0 + e1 + e2 + e3);
  ((float4*)gate)[pos] = make_float4(e0 * inv, e1 * inv, e2 * inv, e3 * inv);
}

// ============== Kernel 3: signature features + projections + head ==============
__device__ __forceinline__ void fma4(float* acc, float xv, float4 wt) {
  acc[0] = fmaf(xv, wt.x, acc[0]);
  acc[1] = fmaf(xv, wt.y, acc[1]);
  acc[2] = fmaf(xv, wt.z, acc[2]);
  acc[3] = fmaf(xv, wt.w, acc[3]);
}

__global__ __launch_bounds__(256, 2) void sig_kernel(
    const float* __restrict__ F, const float* __restrict__ gate,
    const float* __restrict__ p1, const float* __restrict__ p1b,
    const float* __restrict__ p2, const float* __restrict__ p2b,
    const float* __restrict__ p3, const float* __restrict__ p3b,
    const float* __restrict__ p4, const float* __restrict__ p4b,
    const float* __restrict__ w1, const float* __restrict__ b1,
    const float* __restrict__ gam, const float* __restrict__ bet,
    const float* __restrict__ rmean, const float* __restrict__ rvar,
    const float* __restrict__ w2, const float* __restrict__ b2,
    const float* __restrict__ w3, const float* __restrict__ b3,
    float* __restrict__ out) {
  __shared__ float sPhi[16 * 780];  // [lvl1(5) | l2f(25) | l3f(125) | l4f(625)]
  __shared__ float sDw[16 * 50];
  __shared__ float sS[16 * 50];
  __shared__ float sFeat[16 * 5];
  __shared__ float sSig[16 * 68];
  __shared__ float sBn[16 * 65];

  const int tid = threadIdx.x;
  const int posBase = blockIdx.x * 16;

  // ---- Phase 1a-1: windowed increments Dw[r][i] ----
  for (int u = tid; u < 16 * 50; u += 256) {
    int p = u / 50, rr = u % 50;
    int r = rr / 5, i = rr % 5;
    int pos = posBase + p;
    int t = pos & (TT - 1);
    int q = t + r - W;
    float dv = 0.f;
    if (q >= 0) {
      const float* fb = F + (size_t)(pos - t) * 5;
      dv = fb[(q + 1) * 5 + i] - fb[q * 5 + i];
    }
    sDw[u] = dv;
  }
  for (int u = tid; u < 16 * 5; u += 256) {
    sFeat[u] = F[(size_t)posBase * 5 + u];
  }
  __syncthreads();
  // ---- Phase 1a-2: reverse cumsum S, lvl1 ----
  for (int u = tid; u < 16 * 5; u += 256) {
    int p = u / 5, i = u % 5;
    float s = 0.f;
#pragma unroll
    for (int r = W - 1; r >= 0; --r) {
      s += sDw[p * 50 + r * 5 + i];
      sS[p * 50 + r * 5 + i] = s;
    }
    sPhi[p * 780 + i] = s;
  }
  __syncthreads();
  // ---- Phase 1b: l2f[e,f] and l3f[i,e,f] via revcumsum recurrence ----
  for (int u = tid; u < 16 * 25; u += 256) {
    int p = u / 25, ef = u % 25;
    int e = ef / 5, fi = ef % 5;
    const float* dwp = sDw + p * 50;
    const float* sp = sS + p * 50;
    float a = 0.f;  // RA[r][e][fi] running (sum over r' > r)
    float l3a[5] = {0.f, 0.f, 0.f, 0.f, 0.f};
#pragma unroll
    for (int r = W - 1; r >= 0; --r) {
      float aa = a;
#pragma unroll
      for (int i = 0; i < 5; ++i) l3a[i] = fmaf(dwp[r * 5 + i], aa, l3a[i]);
      a = fmaf(dwp[r * 5 + e], sp[r * 5 + fi], a);
    }
    float* php = sPhi + p * 780;
    php[5 + ef] = a;  // l2f
#pragma unroll
    for (int i = 0; i < 5; ++i) php[30 + i * 25 + ef] = l3a[i];
  }
  __syncthreads();
  // ---- Phase 1c: l4f = l2f (x) l2f ----
  for (int u = tid; u < 16 * 625; u += 256) {
    int p = u / 625, a2 = u % 625;
    int i = a2 / 25, j = a2 % 25;
    const float* php = sPhi + p * 780;
    sPhi[p * 780 + 155 + a2] = php[5 + i] * php[5 + j];
  }
  __syncthreads();

  // ---- Phase 2: projections. wave = 16 h-quads x 4 positions ----
  const int lane = tid & 63;
  const int wv = tid >> 6;
  const int hq = lane & 15;
  const int pq = lane >> 4;
  const int pl = wv * 4 + pq;  // local position 0..15
  const int h0 = hq * 4;       // h columns h0..h0+3
  const float* php = sPhi + pl * 780;

  float acc1[4] = {0, 0, 0, 0}, acc2[4] = {0, 0, 0, 0};
  float acc3[4] = {0, 0, 0, 0}, acc4[4] = {0, 0, 0, 0};

#pragma unroll
  for (int k = 0; k < 5; ++k) {
    float xv = php[k];
    float4 wA = *(const float4*)(p1 + k * 64 + h0);
    float4 wB = *(const float4*)(p2 + k * 64 + h0);
    float4 wC = *(const float4*)(p3 + k * 64 + h0);
    float4 wD = *(const float4*)(p4 + k * 64 + h0);
    fma4(acc1, xv, wA);
    fma4(acc2, xv, wB);
    fma4(acc3, xv, wC);
    fma4(acc4, xv, wD);
  }
  for (int k = 5; k < 30; ++k) {
    float xv = php[k];
    float4 wB = *(const float4*)(p2 + k * 64 + h0);
    float4 wC = *(const float4*)(p3 + k * 64 + h0);
    float4 wD = *(const float4*)(p4 + k * 64 + h0);
    fma4(acc2, xv, wB);
    fma4(acc3, xv, wC);
    fma4(acc4, xv, wD);
  }
  for (int k = 30; k < 155; ++k) {
    float xv = php[k];
    float4 wC = *(const float4*)(p3 + k * 64 + h0);
    float4 wD = *(const float4*)(p4 + k * 64 + h0);
    fma4(acc3, xv, wC);
    fma4(acc4, xv, wD);
  }
  {
    float xv = php[155];
    float4 wD = *(const float4*)(p4 + 155 * 64 + h0);
    fma4(acc4, xv, wD);
  }
  for (int k = 156; k < 780; k += 4) {
    float4 xv = *(const float4*)(php + k);
    float4 wD0 = *(const float4*)(p4 + (k + 0) * 64 + h0);
    float4 wD1 = *(const float4*)(p4 + (k + 1) * 64 + h0);
    float4 wD2 = *(const float4*)(p4 + (k + 2) * 64 + h0);
    float4 wD3 = *(const float4*)(p4 + (k + 3) * 64 + h0);
    fma4(acc4, xv.x, wD0);
    fma4(acc4, xv.y, wD1);
    fma4(acc4, xv.z, wD2);
    fma4(acc4, xv.w, wD3);
  }

  // ---- gate combine -> sig_repr in LDS ----
  {
    const int pos = posBase + pl;
    const int t = pos & (TT - 1);
    float4 g = ((const float4*)gate)[pos];
    float g1v = (t >= 1) ? g.y : 0.f;
    float g2v = (t >= 2) ? g.z : 0.f;
    float g3v = (t >= 3) ? g.w : 0.f;
    float4 bA = *(const float4*)(p1b + h0);
    float4 bB = *(const float4*)(p2b + h0);
    float4 bC = *(const float4*)(p3b + h0);
    float4 bD = *(const float4*)(p4b + h0);
    float4 sr;
    sr.x = g.x * (acc1[0] + bA.x) + g1v * (acc2[0] + bB.x) + g2v * (acc3[0] + bC.x) + g3v * (acc4[0] + bD.x);
    sr.y = g.x * (acc1[1] + bA.y) + g1v * (acc2[1] + bB.y) + g2v * (acc3[1] + bC.y) + g3v * (acc4[1] + bD.y);
    sr.z = g.x * (acc1[2] + bA.z) + g1v * (acc2[2] + bB.z) + g2v * (acc3[2] + bC.z) + g3v * (acc4[2] + bD.z);
    sr.w = g.x * (acc1[3] + bA.w) + g1v * (acc2[3] + bB.w) + g2v * (acc3[3] + bC.w) + g3v * (acc4[3] + bD.w);
    *(float4*)(sSig + pl * 68 + h0) = sr;
  }
  __syncthreads();

  // ---- Head: h1 = relu(combined @ w1 + b1), BN. wave wv -> positions wv*4..+3, lane=j ----
  {
    const int j = lane;
    float a0 = b1[j];
    float a1 = a0, a2 = a0, a3 = a0;
    const float* sg0 = sSig + (wv * 4 + 0) * 68;
    const float* sg1 = sSig + (wv * 4 + 1) * 68;
    const float* sg2 = sSig + (wv * 4 + 2) * 68;
    const float* sg3 = sSig + (wv * 4 + 3) * 68;
    for (int i = 0; i < 64; ++i) {
      float wt = w1[i * 64 + j];
      a0 = fmaf(sg0[i], wt, a0);
      a1 = fmaf(sg1[i], wt, a1);
      a2 = fmaf(sg2[i], wt, a2);
      a3 = fmaf(sg3[i], wt, a3);
    }
    const float* ft = sFeat + wv * 4 * 5;
#pragma unroll
    for (int i = 0; i < 5; ++i) {
      float wt = w1[(64 + i) * 64 + j];
      a0 = fmaf(ft[i], wt, a0);
      a1 = fmaf(ft[5 + i], wt, a1);
      a2 = fmaf(ft[10 + i], wt, a2);
      a3 = fmaf(ft[15 + i], wt, a3);
    }
    float sc = gam[j] * rsqrtf(rvar[j] + 1e-5f);
    float rm = rmean[j], be = bet[j];
    sBn[(wv * 4 + 0) * 65 + j] = fmaf(fmaxf(a0, 0.f) - rm, sc, be);
    sBn[(wv * 4 + 1) * 65 + j] = fmaf(fmaxf(a1, 0.f) - rm, sc, be);
    sBn[(wv * 4 + 2) * 65 + j] = fmaf(fmaxf(a2, 0.f) - rm, sc, be);
    sBn[(wv * 4 + 3) * 65 + j] = fmaf(fmaxf(a3, 0.f) - rm, sc, be);
  }
  __syncthreads();

  // ---- h2 = relu(bn @ w2 + b2); out = 1.5*tanh(h2 @ w3 + b3) ----
  const float b3s = b3[0];
  for (int task = tid; task < 512; task += 256) {
    int p = task >> 5, k = task & 31;
    const float* bnp = sBn + p * 65;
    float a = b2[k];
    for (int j = 0; j < 64; ++j) a = fmaf(bnp[j], w2[j * 32 + k], a);
    float partial = fmaxf(a, 0.f) * w3[k];
#pragma unroll
    for (int off = 16; off >= 1; off >>= 1) partial += __shfl_xor(partial, off, 32);
    if (k == 0) out[posBase + p] = 1.5f * tanhf(partial + b3s);
  }
}

extern "C" void kernel_launch(void* const* d_in, const int* in_sizes, int n_in,
                              void* d_out, int out_size, void* d_ws, size_t ws_size,
                              hipStream_t stream) {
  const float* F = (const float*)d_in[0];
  const float* hw1 = (const float*)d_in[1];
  const float* hb1 = (const float*)d_in[2];
  const float* hw2 = (const float*)d_in[3];
  const float* hb2 = (const float*)d_in[4];
  const float* hw3 = (const float*)d_in[5];
  const float* hb3 = (const float*)d_in[6];
  const float* gw1 = (const float*)d_in[7];
  const float* gb1 = (const float*)d_in[8];
  const float* gw2 = (const float*)d_in[9];
  const float* gb2 = (const float*)d_in[10];
  const float* p1 = (const float*)d_in[11];
  const float* p1b = (const float*)d_in[12];
  const float* p2 = (const float*)d_in[13];
  const float* p2b = (const float*)d_in[14];
  const float* p3 = (const float*)d_in[15];
  const float* p3b = (const float*)d_in[16];
  const float* p4 = (const float*)d_in[17];
  const float* p4b = (const float*)d_in[18];
  const float* w1 = (const float*)d_in[19];
  const float* b1 = (const float*)d_in[20];
  const float* gam = (const float*)d_in[21];
  const float* bet = (const float*)d_in[22];
  const float* rmean = (const float*)d_in[23];
  const float* rvar = (const float*)d_in[24];
  const float* w2 = (const float*)d_in[25];
  const float* b2 = (const float*)d_in[26];
  const float* w3 = (const float*)d_in[27];
  const float* b3 = (const float*)d_in[28];

  float* ws = (float*)d_ws;
  float* ret = ws;             // 65536 floats
  float* vol = ws + 65536;     // 65536 floats
  float* gate = ws + 131072;   // 262144 floats (B*T*4)
  float* out = (float*)d_out;  // 65536 floats (B, T)

  prep_kernel<<<32, 256, 0, stream>>>(F, ret, vol);
  gate_kernel<<<256, 256, 0, stream>>>(ret, vol, hw1, hb1, hw2, hb2, hw3, hb3,
                                       gw1, gb1, gw2, gb2, gate);
  sig_kernel<<<4096, 256, 0, stream>>>(F, gate, p1, p1b, p2, p2b, p3, p3b, p4,
                                       p4b, w1, b1, gam, bet, rmean, rvar, w2,
                                       b2, w3, b3, out);
}

// Round 3
// 265.763 us; speedup vs baseline: 2.4341x; 2.4341x over previous
//
#include <hip/hip_runtime.h>
#include <math.h>

#define TT 2048
#define W 10

typedef short bf16x8 __attribute__((ext_vector_type(8)));
typedef float f32x4 __attribute__((ext_vector_type(4)));

__device__ __forceinline__ unsigned short f32_bf16(float f) {
  unsigned int u = __float_as_uint(f);
  u = (u + 0x7fffu + ((u >> 16) & 1u)) >> 16;
  return (unsigned short)u;
}
__device__ __forceinline__ float bf16_f32(unsigned short h) {
  return __uint_as_float(((unsigned int)h) << 16);
}

// ============== Kernel 0: weights -> bf16 hi/lo, [h][k] transposed, K zero-padded ==============
// Layout (ushort elements): L1 @0 (64x32), L2 @2048 (64x32), L3 @4096 (64x160), L4 @14336 (64x800)
__device__ __forceinline__ void wstore(unsigned short* WtH, unsigned short* WtL,
                                       int g, float v) {
  unsigned short hi = f32_bf16(v);
  WtH[g] = hi;
  WtL[g] = f32_bf16(v - bf16_f32(hi));
}

__global__ __launch_bounds__(256) void wprep_kernel(
    const float* __restrict__ p1, const float* __restrict__ p2,
    const float* __restrict__ p3, const float* __restrict__ p4,
    unsigned short* __restrict__ WtH, unsigned short* __restrict__ WtL) {
  int g = blockIdx.x * 256 + threadIdx.x;  // 0..65535
  if (g < 2048) {
    int h = g / 32, k = g % 32;
    wstore(WtH, WtL, g, (k < 5) ? p1[k * 64 + h] : 0.f);
  } else if (g < 4096) {
    int loc = g - 2048, h = loc / 32, k = loc % 32;
    wstore(WtH, WtL, g, (k < 30) ? p2[k * 64 + h] : 0.f);
  } else if (g < 14336) {
    int loc = g - 4096, h = loc / 160, k = loc % 160;
    wstore(WtH, WtL, g, (k < 155) ? p3[k * 64 + h] : 0.f);
  } else {
    int loc = g - 14336, h = loc / 800, k = loc % 800;
    wstore(WtH, WtL, g, (k < 780) ? p4[k * 64 + h] : 0.f);
  }
}

// ============== Kernel 1: returns + running vol (per-row scan) ==============
__global__ __launch_bounds__(256) void prep_kernel(const float* __restrict__ F,
                                                   float* __restrict__ ret,
                                                   float* __restrict__ vol) {
  __shared__ float sAbs[TT];
  __shared__ float sPart[256];
  const int b = blockIdx.x, tid = threadIdx.x;
  const float* fb = F + (size_t)b * TT * 5;
#pragma unroll
  for (int u = 0; u < 8; ++u) {
    int t = u * 256 + tid;
    float rv = 0.f;
    if (t > 0) rv = fb[t * 5] - fb[(t - 1) * 5];
    ret[b * TT + t] = rv;
    sAbs[t] = fabsf(rv);
  }
  __syncthreads();
  float loc[8];
  float run = 0.f;
#pragma unroll
  for (int u = 0; u < 8; ++u) { run += sAbs[tid * 8 + u]; loc[u] = run; }
  sPart[tid] = run;
  __syncthreads();
  for (int off = 1; off < 256; off <<= 1) {
    float v = (tid >= off) ? sPart[tid - off] : 0.f;
    __syncthreads();
    sPart[tid] += v;
    __syncthreads();
  }
  float excl = sPart[tid] - run;
#pragma unroll
  for (int u = 0; u < 8; ++u) {
    int t = tid * 8 + u;
    vol[b * TT + t] = (excl + loc[u]) / ((float)(t + 1) + 1e-8f);
  }
}

// ============== Kernel 2: H MLP + regime gate softmax ==============
__global__ __launch_bounds__(256) void gate_kernel(
    const float* __restrict__ ret, const float* __restrict__ vol,
    const float* __restrict__ hw1, const float* __restrict__ hb1,
    const float* __restrict__ hw2, const float* __restrict__ hb2,
    const float* __restrict__ hw3, const float* __restrict__ hb3,
    const float* __restrict__ gw1, const float* __restrict__ gb1,
    const float* __restrict__ gw2, const float* __restrict__ gb2,
    float* __restrict__ gate) {
  const int pos = blockIdx.x * 256 + threadIdx.x;
  const int t = pos & (TT - 1);
  const int start = (t >= W) ? (t - W) : 0;
  const float* rp = ret + (pos - t) + start;
  float r[W];
#pragma unroll
  for (int u = 0; u < W; ++u) r[u] = rp[u];
  float h1v[32];
#pragma unroll
  for (int j = 0; j < 32; ++j) {
    float a = hb1[j];
#pragma unroll
    for (int u = 0; u < W; ++u) a = fmaf(r[u], hw1[u * 32 + j], a);
    h1v[j] = fmaxf(a, 0.f);
  }
  float hs = hb3[0];
#pragma unroll
  for (int j = 0; j < 32; ++j) {
    float a = hb2[j];
#pragma unroll
    for (int u = 0; u < 32; ++u) a = fmaf(h1v[u], hw2[u * 32 + j], a);
    hs = fmaf(fmaxf(a, 0.f), hw3[j], hs);
  }
  const float H = 0.5f / (1.f + expf(-hs));
  const float vv = vol[pos];
  float l0 = gb2[0], l1 = gb2[1], l2 = gb2[2], l3 = gb2[3];
#pragma unroll
  for (int j = 0; j < 32; ++j) {
    float z = fmaxf(fmaf(H, gw1[j], fmaf(vv, gw1[32 + j], gb1[j])), 0.f);
    l0 = fmaf(z, gw2[j * 4 + 0], l0);
    l1 = fmaf(z, gw2[j * 4 + 1], l1);
    l2 = fmaf(z, gw2[j * 4 + 2], l2);
    l3 = fmaf(z, gw2[j * 4 + 3], l3);
  }
  float m = fmaxf(fmaxf(l0, l1), fmaxf(l2, l3));
  float e0 = expf(l0 - m), e1 = expf(l1 - m), e2 = expf(l2 - m), e3 = expf(l3 - m);
  float inv = 1.f / (e0 + e1 + e2 + e3);
  ((float4*)gate)[pos] = make_float4(e0 * inv, e1 * inv, e2 * inv, e3 * inv);
}

// ============== Kernel 3: signature features (bf16 hi/lo) + MFMA projections + head ==============
#define MFMA16(a, b, c) __builtin_amdgcn_mfma_f32_16x16x32_bf16((a), (b), (c), 0, 0, 0)

__global__ __launch_bounds__(256, 2) void sig_kernel(
    const float* __restrict__ F, const float* __restrict__ gate,
    const unsigned short* __restrict__ WtH, const unsigned short* __restrict__ WtL,
    const float* __restrict__ p1b, const float* __restrict__ p2b,
    const float* __restrict__ p3b, const float* __restrict__ p4b,
    const float* __restrict__ w1, const float* __restrict__ b1,
    const float* __restrict__ gam, const float* __restrict__ bet,
    const float* __restrict__ rmean, const float* __restrict__ rvar,
    const float* __restrict__ w2, const float* __restrict__ b2,
    const float* __restrict__ w3, const float* __restrict__ b3,
    float* __restrict__ out) {
  // phi rows padded to 808 bf16 (1616 B): 16B-aligned rows, 2-way max LDS bank aliasing
  __shared__ unsigned short phiH[16][808];
  __shared__ unsigned short phiL[16][808];
  __shared__ float sUnion[2128];  // phase1: sDw(800)+sS(800)+sL2(400); epilogue: sSig(1088)+sBn(1040)
  __shared__ float sFeat[80];

  float* sDw = sUnion;
  float* sS = sUnion + 800;
  float* sL2 = sUnion + 1600;

  const int tid = threadIdx.x;
  const int posBase = blockIdx.x * 16;

  // ---- Phase 1a-1: windowed increments Dw[p][r][i] ----
  for (int u = tid; u < 800; u += 256) {
    int p = u / 50, rr = u % 50;
    int r = rr / 5, i = rr % 5;
    int pos = posBase + p;
    int t = pos & (TT - 1);
    int q = t + r - W;
    float dv = 0.f;
    if (q >= 0) {
      const float* fb = F + (size_t)(pos - t) * 5;
      dv = fb[(q + 1) * 5 + i] - fb[q * 5 + i];
    }
    sDw[u] = dv;
  }
  for (int u = tid; u < 80; u += 256) sFeat[u] = F[(size_t)posBase * 5 + u];
  __syncthreads();

  // ---- Phase 1a-2: reverse cumsum S; lvl1 -> phi[0..5) ----
  for (int u = tid; u < 80; u += 256) {
    int p = u / 5, i = u % 5;
    float s = 0.f;
#pragma unroll
    for (int r = W - 1; r >= 0; --r) {
      s += sDw[p * 50 + r * 5 + i];
      sS[p * 50 + r * 5 + i] = s;
    }
    unsigned short hi = f32_bf16(s);
    phiH[p][i] = hi;
    phiL[p][i] = f32_bf16(s - bf16_f32(hi));
  }
  __syncthreads();

  // ---- Phase 1b: l2f -> phi[5..30) (+ fp32 copy), l3f -> phi[30..155) ----
  for (int u = tid; u < 400; u += 256) {
    int p = u / 25, ef = u % 25;
    int e = ef / 5, fi = ef % 5;
    const float* dwp = sDw + p * 50;
    const float* sp = sS + p * 50;
    float a = 0.f;
    float l3a[5] = {0.f, 0.f, 0.f, 0.f, 0.f};
#pragma unroll
    for (int r = W - 1; r >= 0; --r) {
      float aa = a;
#pragma unroll
      for (int i = 0; i < 5; ++i) l3a[i] = fmaf(dwp[r * 5 + i], aa, l3a[i]);
      a = fmaf(dwp[r * 5 + e], sp[r * 5 + fi], a);
    }
    sL2[p * 25 + ef] = a;
    unsigned short hi = f32_bf16(a);
    phiH[p][5 + ef] = hi;
    phiL[p][5 + ef] = f32_bf16(a - bf16_f32(hi));
#pragma unroll
    for (int i = 0; i < 5; ++i) {
      int kk = 30 + i * 25 + ef;
      unsigned short h2i = f32_bf16(l3a[i]);
      phiH[p][kk] = h2i;
      phiL[p][kk] = f32_bf16(l3a[i] - bf16_f32(h2i));
    }
  }
  __syncthreads();

  // ---- Phase 1c: l4f = l2f (x) l2f -> phi[155..780); zero pad [780..808) ----
  for (int u = tid; u < 16 * 625; u += 256) {
    int p = u / 625, a2 = u % 625;
    float v = sL2[p * 25 + a2 / 25] * sL2[p * 25 + a2 % 25];
    int kk = 155 + a2;
    unsigned short hi = f32_bf16(v);
    phiH[p][kk] = hi;
    phiL[p][kk] = f32_bf16(v - bf16_f32(hi));
  }
  for (int u = tid; u < 16 * 28; u += 256) {
    int p = u / 28, kk = 780 + u % 28;
    phiH[p][kk] = 0;
    phiL[p][kk] = 0;
  }
  __syncthreads();

  // ---- Phase 2: MFMA projections. wave wv -> h-tile [wv*16, wv*16+16) ----
  const int lane = tid & 63, wv = tid >> 6;
  const int col = lane & 15, quad = lane >> 4;
  const int hw = wv * 16;

  const unsigned short* a4H = WtH + 14336 + (hw + col) * 800 + quad * 8;
  const unsigned short* a4L = WtL + 14336 + (hw + col) * 800 + quad * 8;
  const unsigned short* a3H = WtH + 4096 + (hw + col) * 160 + quad * 8;
  const unsigned short* a3L = WtL + 4096 + (hw + col) * 160 + quad * 8;
  const unsigned short* a2H = WtH + 2048 + (hw + col) * 32 + quad * 8;
  const unsigned short* a2L = WtL + 2048 + (hw + col) * 32 + quad * 8;
  const unsigned short* a1H = WtH + 0 + (hw + col) * 32 + quad * 8;
  const unsigned short* a1L = WtL + 0 + (hw + col) * 32 + quad * 8;
  const unsigned short* bH = &phiH[col][quad * 8];
  const unsigned short* bL = &phiL[col][quad * 8];

  f32x4 acc4a = {0.f, 0.f, 0.f, 0.f}, acc4b = {0.f, 0.f, 0.f, 0.f};
  f32x4 acc3a = {0.f, 0.f, 0.f, 0.f}, acc3b = {0.f, 0.f, 0.f, 0.f};
  f32x4 acc2 = {0.f, 0.f, 0.f, 0.f}, acc1 = {0.f, 0.f, 0.f, 0.f};

  for (int s = 0; s < 25; ++s) {
    bf16x8 bh = *(const bf16x8*)(bH + s * 32);
    bf16x8 bl = *(const bf16x8*)(bL + s * 32);
    bf16x8 ah = *(const bf16x8*)(a4H + s * 32);
    bf16x8 al = *(const bf16x8*)(a4L + s * 32);
    acc4a = MFMA16(ah, bh, acc4a);
    acc4b = MFMA16(ah, bl, acc4b);
    acc4b = MFMA16(al, bh, acc4b);
    if (s < 5) {
      bf16x8 ch = *(const bf16x8*)(a3H + s * 32);
      bf16x8 cl = *(const bf16x8*)(a3L + s * 32);
      acc3a = MFMA16(ch, bh, acc3a);
      acc3b = MFMA16(ch, bl, acc3b);
      acc3b = MFMA16(cl, bh, acc3b);
      if (s == 0) {
        bf16x8 dh = *(const bf16x8*)a2H;
        bf16x8 dl = *(const bf16x8*)a2L;
        acc2 = MFMA16(dh, bh, acc2);
        acc2 = MFMA16(dh, bl, acc2);
        acc2 = MFMA16(dl, bh, acc2);
        bf16x8 eh = *(const bf16x8*)a1H;
        bf16x8 el = *(const bf16x8*)a1L;
        acc1 = MFMA16(eh, bh, acc1);
        acc1 = MFMA16(eh, bl, acc1);
        acc1 = MFMA16(el, bh, acc1);
      }
    }
  }

  // ---- gate combine -> sig_repr in LDS (C/D layout: col=lane&15 -> pos, row=quad*4+reg -> h) ----
  float* sSig = sUnion;         // [16][68]
  float* sBn = sUnion + 1088;   // [16][65]
  {
    f32x4 a4 = acc4a + acc4b;
    f32x4 a3 = acc3a + acc3b;
    const int pl = col;
    const int pos = posBase + pl;
    const int t = pos & (TT - 1);
    float4 g = ((const float4*)gate)[pos];
    float g0 = g.x;
    float g1 = (t >= 1) ? g.y : 0.f;
    float g2 = (t >= 2) ? g.z : 0.f;
    float g3 = (t >= 3) ? g.w : 0.f;
#pragma unroll
    for (int r = 0; r < 4; ++r) {
      int h = hw + quad * 4 + r;
      float v = g0 * (acc1[r] + p1b[h]) + g1 * (acc2[r] + p2b[h]) +
                g2 * (a3[r] + p3b[h]) + g3 * (a4[r] + p4b[h]);
      sSig[pl * 68 + h] = v;
    }
  }
  __syncthreads();

  // ---- Head: h1 = relu(combined @ w1 + b1) -> BN. wave wv -> positions wv*4..+3, lane=j ----
  {
    const int j = lane;
    float a0 = b1[j];
    float a1 = a0, a2 = a0, a3 = a0;
    const float* sg0 = sSig + (wv * 4 + 0) * 68;
    const float* sg1 = sSig + (wv * 4 + 1) * 68;
    const float* sg2 = sSig + (wv * 4 + 2) * 68;
    const float* sg3 = sSig + (wv * 4 + 3) * 68;
    for (int i = 0; i < 64; ++i) {
      float wt = w1[i * 64 + j];
      a0 = fmaf(sg0[i], wt, a0);
      a1 = fmaf(sg1[i], wt, a1);
      a2 = fmaf(sg2[i], wt, a2);
      a3 = fmaf(sg3[i], wt, a3);
    }
    const float* ft = sFeat + wv * 4 * 5;
#pragma unroll
    for (int i = 0; i < 5; ++i) {
      float wt = w1[(64 + i) * 64 + j];
      a0 = fmaf(ft[i], wt, a0);
      a1 = fmaf(ft[5 + i], wt, a1);
      a2 = fmaf(ft[10 + i], wt, a2);
      a3 = fmaf(ft[15 + i], wt, a3);
    }
    float sc = gam[j] * rsqrtf(rvar[j] + 1e-5f);
    float rm = rmean[j], be = bet[j];
    sBn[(wv * 4 + 0) * 65 + j] = fmaf(fmaxf(a0, 0.f) - rm, sc, be);
    sBn[(wv * 4 + 1) * 65 + j] = fmaf(fmaxf(a1, 0.f) - rm, sc, be);
    sBn[(wv * 4 + 2) * 65 + j] = fmaf(fmaxf(a2, 0.f) - rm, sc, be);
    sBn[(wv * 4 + 3) * 65 + j] = fmaf(fmaxf(a3, 0.f) - rm, sc, be);
  }
  __syncthreads();

  // ---- h2 = relu(bn @ w2 + b2); out = 1.5*tanh(h2 @ w3 + b3) ----
  const float b3s = b3[0];
  for (int task = tid; task < 512; task += 256) {
    int p = task >> 5, k = task & 31;
    const float* bnp = sBn + p * 65;
    float a = b2[k];
    for (int j = 0; j < 64; ++j) a = fmaf(bnp[j], w2[j * 32 + k], a);
    float partial = fmaxf(a, 0.f) * w3[k];
#pragma unroll
    for (int off = 16; off >= 1; off >>= 1) partial += __shfl_xor(partial, off, 32);
    if (k == 0) out[posBase + p] = 1.5f * tanhf(partial + b3s);
  }
}

extern "C" void kernel_launch(void* const* d_in, const int* in_sizes, int n_in,
                              void* d_out, int out_size, void* d_ws, size_t ws_size,
                              hipStream_t stream) {
  const float* F = (const float*)d_in[0];
  const float* hw1 = (const float*)d_in[1];
  const float* hb1 = (const float*)d_in[2];
  const float* hw2 = (const float*)d_in[3];
  const float* hb2 = (const float*)d_in[4];
  const float* hw3 = (const float*)d_in[5];
  const float* hb3 = (const float*)d_in[6];
  const float* gw1 = (const float*)d_in[7];
  const float* gb1 = (const float*)d_in[8];
  const float* gw2 = (const float*)d_in[9];
  const float* gb2 = (const float*)d_in[10];
  const float* p1 = (const float*)d_in[11];
  const float* p1b = (const float*)d_in[12];
  const float* p2 = (const float*)d_in[13];
  const float* p2b = (const float*)d_in[14];
  const float* p3 = (const float*)d_in[15];
  const float* p3b = (const float*)d_in[16];
  const float* p4 = (const float*)d_in[17];
  const float* p4b = (const float*)d_in[18];
  const float* w1 = (const float*)d_in[19];
  const float* b1 = (const float*)d_in[20];
  const float* gam = (const float*)d_in[21];
  const float* bet = (const float*)d_in[22];
  const float* rmean = (const float*)d_in[23];
  const float* rvar = (const float*)d_in[24];
  const float* w2 = (const float*)d_in[25];
  const float* b2 = (const float*)d_in[26];
  const float* w3 = (const float*)d_in[27];
  const float* b3 = (const float*)d_in[28];

  float* ws = (float*)d_ws;
  float* ret = ws;             // 65536 floats
  float* vol = ws + 65536;     // 65536 floats
  float* gate = ws + 131072;   // 262144 floats (B*T*4)
  unsigned short* WtH = (unsigned short*)(ws + 393216);  // 65536 ushorts (131072 B)
  unsigned short* WtL = WtH + 65536;                     // 65536 ushorts
  float* out = (float*)d_out;  // 65536 floats (B, T)

  wprep_kernel<<<256, 256, 0, stream>>>(p1, p2, p3, p4, WtH, WtL);
  prep_kernel<<<32, 256, 0, stream>>>(F, ret, vol);
  gate_kernel<<<256, 256, 0, stream>>>(ret, vol, hw1, hb1, hw2, hb2, hw3, hb3,
                                       gw1, gb1, gw2, gb2, gate);
  sig_kernel<<<4096, 256, 0, stream>>>(F, gate, WtH, WtL, p1b, p2b, p3b, p4b,
                                       w1, b1, gam, bet, rmean, rvar, w2, b2,
                                       w3, b3, out);
}

// Round 4
// 245.684 us; speedup vs baseline: 2.6330x; 1.0817x over previous
//
#include <hip/hip_runtime.h>
#include <math.h>

#define TT 2048
#define W 10

typedef short bf16x8 __attribute__((ext_vector_type(8)));
typedef float f32x4 __attribute__((ext_vector_type(4)));

// Truncation-based hi/lo bf16 split: hi = trunc(v), lo = trunc(v - hi).
// v - hi is exact in fp32; residual after hi+lo <= 2^-16 |v|. lo catches the
// truncation error, so rounding hi would buy nothing. ~4 VALU vs ~10 for RNE.
__device__ __forceinline__ void splitTrunc(float v, unsigned short& hi,
                                           unsigned short& lo) {
  unsigned int u = __float_as_uint(v);
  hi = (unsigned short)(u >> 16);
  float r = v - __uint_as_float(u & 0xffff0000u);
  lo = (unsigned short)(__float_as_uint(r) >> 16);
}

// ============== Kernel 1: fused [wprep | prep+gate] ==============
// blocks [0,256): gate for one (row, 256-pos chunk); redundant per-block scan.
// blocks [256,512): weight repack to bf16 hi/lo, transposed [h][k], K padded.
// Wt layout (ushort): W1 @0 (64x32), W2 @2048 (64x32), W3 @4096 (64x160),
// W4 @14336 (64x800) with phi-k mapping: k<155 -> p4 row k; [155,160) zero;
// [160,785) -> p4 row k-5; [785,800) zero.  (l4f lives at phi k=160 so that
// phase-1c writes are even-aligned for packed b32 LDS stores.)
__global__ __launch_bounds__(256) void pre_kernel(
    const float* __restrict__ F,
    const float* __restrict__ hw1, const float* __restrict__ hb1,
    const float* __restrict__ hw2, const float* __restrict__ hb2,
    const float* __restrict__ hw3, const float* __restrict__ hb3,
    const float* __restrict__ gw1, const float* __restrict__ gb1,
    const float* __restrict__ gw2, const float* __restrict__ gb2,
    const float* __restrict__ p1, const float* __restrict__ p2,
    const float* __restrict__ p3, const float* __restrict__ p4,
    unsigned short* __restrict__ WtH, unsigned short* __restrict__ WtL,
    float* __restrict__ gate) {
  const int bid = blockIdx.x;
  const int tid = threadIdx.x;
  if (bid >= 256) {
    int g = (bid - 256) * 256 + tid;
    float v;
    if (g < 2048) {
      int h = g >> 5, k = g & 31;
      v = (k < 5) ? p1[k * 64 + h] : 0.f;
    } else if (g < 4096) {
      int loc = g - 2048, h = loc >> 5, k = loc & 31;
      v = (k < 30) ? p2[k * 64 + h] : 0.f;
    } else if (g < 14336) {
      int loc = g - 4096, h = loc / 160, k = loc - h * 160;
      v = (k < 155) ? p3[k * 64 + h] : 0.f;
    } else {
      int loc = g - 14336, h = loc / 800, k = loc - h * 800;
      if (k < 155) v = p4[k * 64 + h];
      else if (k >= 160 && k < 785) v = p4[(k - 5) * 64 + h];
      else v = 0.f;
    }
    unsigned short hi, lo;
    splitTrunc(v, hi, lo);
    WtH[g] = hi;
    WtL[g] = lo;
    return;
  }
  // ---- gate block: row b, positions [t0, t0+256) ----
  __shared__ float sRet[TT];
  __shared__ float sCum[TT];
  __shared__ float sPart[256];
  const int b = bid >> 3;
  const int t0 = (bid & 7) << 8;
  const float* fb = F + (size_t)b * TT * 5;
#pragma unroll
  for (int u = 0; u < 8; ++u) {
    int t = u * 256 + tid;
    sRet[t] = (t > 0) ? (fb[t * 5] - fb[(t - 1) * 5]) : 0.f;
  }
  __syncthreads();
  float loc8[8], run = 0.f;
#pragma unroll
  for (int u = 0; u < 8; ++u) {
    run += fabsf(sRet[tid * 8 + u]);
    loc8[u] = run;
  }
  sPart[tid] = run;
  __syncthreads();
  for (int off = 1; off < 256; off <<= 1) {
    float v = (tid >= off) ? sPart[tid - off] : 0.f;
    __syncthreads();
    sPart[tid] += v;
    __syncthreads();
  }
  float excl = sPart[tid] - run;
#pragma unroll
  for (int u = 0; u < 8; ++u) sCum[tid * 8 + u] = excl + loc8[u];
  __syncthreads();
  // ---- gate MLP at t = t0 + tid ----
  const int t = t0 + tid;
  const float vv = sCum[t] / ((float)(t + 1) + 1e-8f);
  const int start = (t >= W) ? (t - W) : 0;
  float r[W];
#pragma unroll
  for (int u = 0; u < W; ++u) r[u] = sRet[start + u];
  float h1v[32];
#pragma unroll
  for (int j = 0; j < 32; ++j) {
    float a = hb1[j];
#pragma unroll
    for (int u = 0; u < W; ++u) a = fmaf(r[u], hw1[u * 32 + j], a);
    h1v[j] = fmaxf(a, 0.f);
  }
  float hs = hb3[0];
#pragma unroll
  for (int j = 0; j < 32; ++j) {
    float a = hb2[j];
#pragma unroll
    for (int u = 0; u < 32; ++u) a = fmaf(h1v[u], hw2[u * 32 + j], a);
    hs = fmaf(fmaxf(a, 0.f), hw3[j], hs);
  }
  const float H = 0.5f / (1.f + expf(-hs));
  float l0 = gb2[0], l1 = gb2[1], l2 = gb2[2], l3 = gb2[3];
#pragma unroll
  for (int j = 0; j < 32; ++j) {
    float z = fmaxf(fmaf(H, gw1[j], fmaf(vv, gw1[32 + j], gb1[j])), 0.f);
    l0 = fmaf(z, gw2[j * 4 + 0], l0);
    l1 = fmaf(z, gw2[j * 4 + 1], l1);
    l2 = fmaf(z, gw2[j * 4 + 2], l2);
    l3 = fmaf(z, gw2[j * 4 + 3], l3);
  }
  float m = fmaxf(fmaxf(l0, l1), fmaxf(l2, l3));
  float e0 = expf(l0 - m), e1 = expf(l1 - m), e2 = expf(l2 - m),
        e3 = expf(l3 - m);
  float inv = 1.f / (e0 + e1 + e2 + e3);
  ((float4*)gate)[b * TT + t] = make_float4(e0 * inv, e1 * inv, e2 * inv, e3 * inv);
}

// ============== Kernel 2: signature phi (bf16 hi/lo) + MFMA + head ==============
// 512 threads = 8 waves = 4 h-tiles x 2 K-groups (48 MFMAs each).
// Gate-combine is linear => each K-group folds its partial projections with
// the gate immediately; only one f32x4/lane crosses LDS for the reduction.
#define MFMA16(a, b, c) __builtin_amdgcn_mfma_f32_16x16x32_bf16((a), (b), (c), 0, 0, 0)

__global__ __launch_bounds__(512, 4) void sig_kernel(
    const float* __restrict__ F, const float* __restrict__ gate,
    const unsigned short* __restrict__ WtH, const unsigned short* __restrict__ WtL,
    const float* __restrict__ p1b, const float* __restrict__ p2b,
    const float* __restrict__ p3b, const float* __restrict__ p4b,
    const float* __restrict__ w1, const float* __restrict__ b1,
    const float* __restrict__ gam, const float* __restrict__ bet,
    const float* __restrict__ rmean, const float* __restrict__ rvar,
    const float* __restrict__ w2, const float* __restrict__ b2,
    const float* __restrict__ w3, const float* __restrict__ b3,
    float* __restrict__ out) {
  // phi rows: 808-ushort stride (1616 B): 16B-aligned rows, 2-way-max bank
  // aliasing on b128 fragment reads (free per m136).
  __shared__ unsigned short phiH[16][808];
  __shared__ unsigned short phiL[16][808];
  // sX union: phase1 sDw[0,800) sS[800,1600) sL2[1600,2000)
  //           epilogue sAcc[0,1024) sSig[1024,2112) sBn[2112,3152)
  __shared__ __align__(16) float sX[3152];
  __shared__ float sFeat[80];

  float* sDw = sX;
  float* sS = sX + 800;
  float* sL2 = sX + 1600;

  const int tid = threadIdx.x;
  const int posBase = blockIdx.x * 16;

  // ---- Phase 1a-1: windowed increments Dw[p][r][i] ----
  for (int u = tid; u < 800; u += 512) {
    int p = u / 50, rr = u - p * 50;
    int r = rr / 5, i = rr - r * 5;
    int pos = posBase + p;
    int t = pos & (TT - 1);
    int q = t + r - W;
    float dv = 0.f;
    if (q >= 0) {
      const float* fb = F + (size_t)(pos - t) * 5;
      dv = fb[(q + 1) * 5 + i] - fb[q * 5 + i];
    }
    sDw[u] = dv;
  }
  if (tid < 80) sFeat[tid] = F[(size_t)posBase * 5 + tid];
  __syncthreads();

  // ---- Phase 1a-2: reverse cumsum S; lvl1 -> phi[0..5) ----
  if (tid < 80) {
    int p = tid / 5, i = tid - (tid / 5) * 5;
    float s = 0.f;
#pragma unroll
    for (int r = W - 1; r >= 0; --r) {
      s += sDw[p * 50 + r * 5 + i];
      sS[p * 50 + r * 5 + i] = s;
    }
    unsigned short hi, lo;
    splitTrunc(s, hi, lo);
    phiH[p][i] = hi;
    phiL[p][i] = lo;
  }
  __syncthreads();

  // ---- Phase 1b: l2f -> phi[5..30) + sL2, l3f -> phi[30..155) ----
  if (tid < 400) {
    int p = tid / 25, ef = tid - (tid / 25) * 25;
    int e = ef / 5, fi = ef - e * 5;
    const float* dwp = sDw + p * 50;
    const float* sp = sS + p * 50;
    float a = 0.f;
    float l3a[5] = {0.f, 0.f, 0.f, 0.f, 0.f};
#pragma unroll
    for (int r = W - 1; r >= 0; --r) {
      float aa = a;
#pragma unroll
      for (int i = 0; i < 5; ++i) l3a[i] = fmaf(dwp[r * 5 + i], aa, l3a[i]);
      a = fmaf(dwp[r * 5 + e], sp[r * 5 + fi], a);
    }
    sL2[p * 25 + ef] = a;
    unsigned short hi, lo;
    splitTrunc(a, hi, lo);
    phiH[p][5 + ef] = hi;
    phiL[p][5 + ef] = lo;
#pragma unroll
    for (int i = 0; i < 5; ++i) {
      splitTrunc(l3a[i], hi, lo);
      phiH[p][30 + i * 25 + ef] = hi;
      phiL[p][30 + i * 25 + ef] = lo;
    }
  }
  // zero pads: phi[155..160) and phi[785..800) (disjoint from 1b's writes)
  if (tid < 320) {
    int p = tid / 20, mm = tid - (tid / 20) * 20;
    int kk = (mm < 5) ? (155 + mm) : (780 + mm);
    phiH[p][kk] = 0;
    phiL[p][kk] = 0;
  }
  __syncthreads();

  // ---- Phase 1c: l4f[a2] = l2[i]*l2[j] -> phi[160+a2), packed b32 writes ----
  {
    int p = tid >> 5, t32 = tid & 31;
    int base = t32 * 20;
    int count = (t32 == 31) ? 5 : 20;
    const float* l2p = sL2 + p * 25;
    int i = base / 25, j = base - i * 25;
    unsigned short* rowH = &phiH[p][160 + base];
    unsigned short* rowL = &phiL[p][160 + base];
    int mEnd = count & ~1;
    for (int m = 0; m < mEnd; m += 2) {
      float v0 = l2p[i] * l2p[j];
      j++; if (j == 25) { j = 0; i++; }
      float v1 = l2p[i] * l2p[j];
      j++; if (j == 25) { j = 0; i++; }
      unsigned short h0, lo0, h1, lo1;
      splitTrunc(v0, h0, lo0);
      splitTrunc(v1, h1, lo1);
      *(unsigned int*)(rowH + m) = (unsigned int)h0 | ((unsigned int)h1 << 16);
      *(unsigned int*)(rowL + m) = (unsigned int)lo0 | ((unsigned int)lo1 << 16);
    }
    if (count & 1) {
      float v0 = l2p[i] * l2p[j];
      unsigned short h0, lo0;
      splitTrunc(v0, h0, lo0);
      rowH[mEnd] = h0;
      rowL[mEnd] = lo0;
    }
  }
  __syncthreads();

  // ---- Phase 2: MFMA. wave = (h-tile ht, K-group kg) ----
  const int lane = tid & 63;
  const int wvAll = tid >> 6;  // 0..7
  const int ht = wvAll & 3, kg = wvAll >> 2;
  const int col = lane & 15, quad = lane >> 4;
  const int hw = ht * 16;
  const int arow = hw + col;

  const unsigned short* bHp = &phiH[col][quad * 8];
  const unsigned short* bLp = &phiL[col][quad * 8];
  const unsigned short* a4H = WtH + 14336 + arow * 800 + quad * 8;
  const unsigned short* a4L = WtL + 14336 + arow * 800 + quad * 8;

  f32x4 acc4a = {0.f, 0.f, 0.f, 0.f}, acc4b = {0.f, 0.f, 0.f, 0.f};
  f32x4 acc3a = {0.f, 0.f, 0.f, 0.f}, acc3b = {0.f, 0.f, 0.f, 0.f};
  f32x4 acc2 = {0.f, 0.f, 0.f, 0.f}, acc1 = {0.f, 0.f, 0.f, 0.f};

  if (kg == 0) {  // L4 s in [0,16): 48 MFMAs
    for (int s = 0; s < 16; ++s) {
      bf16x8 bh = *(const bf16x8*)(bHp + s * 32);
      bf16x8 bl = *(const bf16x8*)(bLp + s * 32);
      bf16x8 ah = *(const bf16x8*)(a4H + s * 32);
      bf16x8 al = *(const bf16x8*)(a4L + s * 32);
      acc4a = MFMA16(ah, bh, acc4a);
      acc4b = MFMA16(ah, bl, acc4b);
      acc4b = MFMA16(al, bh, acc4b);
    }
  } else {  // L4 s in [16,25) + L3 + L2 + L1: 48 MFMAs
    for (int s = 16; s < 25; ++s) {
      bf16x8 bh = *(const bf16x8*)(bHp + s * 32);
      bf16x8 bl = *(const bf16x8*)(bLp + s * 32);
      bf16x8 ah = *(const bf16x8*)(a4H + s * 32);
      bf16x8 al = *(const bf16x8*)(a4L + s * 32);
      acc4a = MFMA16(ah, bh, acc4a);
      acc4b = MFMA16(ah, bl, acc4b);
      acc4b = MFMA16(al, bh, acc4b);
    }
    const unsigned short* a3H = WtH + 4096 + arow * 160 + quad * 8;
    const unsigned short* a3L = WtL + 4096 + arow * 160 + quad * 8;
    for (int s = 0; s < 5; ++s) {
      bf16x8 bh = *(const bf16x8*)(bHp + s * 32);
      bf16x8 bl = *(const bf16x8*)(bLp + s * 32);
      bf16x8 ch = *(const bf16x8*)(a3H + s * 32);
      bf16x8 cl = *(const bf16x8*)(a3L + s * 32);
      acc3a = MFMA16(ch, bh, acc3a);
      acc3b = MFMA16(ch, bl, acc3b);
      acc3b = MFMA16(cl, bh, acc3b);
    }
    bf16x8 bh0 = *(const bf16x8*)(bHp);
    bf16x8 bl0 = *(const bf16x8*)(bLp);
    const unsigned short* a2H = WtH + 2048 + arow * 32 + quad * 8;
    const unsigned short* a2L = WtL + 2048 + arow * 32 + quad * 8;
    bf16x8 dh = *(const bf16x8*)a2H;
    bf16x8 dl = *(const bf16x8*)a2L;
    acc2 = MFMA16(dh, bh0, acc2);
    acc2 = MFMA16(dh, bl0, acc2);
    acc2 = MFMA16(dl, bh0, acc2);
    const unsigned short* a1H = WtH + arow * 32 + quad * 8;
    const unsigned short* a1L = WtL + arow * 32 + quad * 8;
    bf16x8 eh = *(const bf16x8*)a1H;
    bf16x8 el = *(const bf16x8*)a1L;
    acc1 = MFMA16(eh, bh0, acc1);
    acc1 = MFMA16(eh, bl0, acc1);
    acc1 = MFMA16(el, bh0, acc1);
  }

  // ---- gate-combine partials; reduce K-groups via LDS ----
  const int pos = posBase + col;
  const int t = pos & (TT - 1);
  float4 g = ((const float4*)gate)[pos];
  const float g0 = g.x;
  const float g1 = (t >= 1) ? g.y : 0.f;
  const float g2 = (t >= 2) ? g.z : 0.f;
  const float g3 = (t >= 3) ? g.w : 0.f;

  if (kg == 1) {
    f32x4 a4 = acc4a + acc4b;
    f32x4 a3 = acc3a + acc3b;
    f32x4 v;
#pragma unroll
    for (int r = 0; r < 4; ++r)
      v[r] = g0 * acc1[r] + g1 * acc2[r] + g2 * a3[r] + g3 * a4[r];
    *(f32x4*)&sX[(ht * 64 + lane) * 4] = v;
  }
  __syncthreads();
  if (kg == 0) {
    f32x4 a4 = acc4a + acc4b;
    f32x4 vo = *(const f32x4*)&sX[(ht * 64 + lane) * 4];
    float* sSig = sX + 1024;  // [16][68]
#pragma unroll
    for (int r = 0; r < 4; ++r) {
      int h = hw + quad * 4 + r;
      float bias = g0 * p1b[h] + g1 * p2b[h] + g2 * p3b[h] + g3 * p4b[h];
      sSig[col * 68 + h] = vo[r] + g3 * a4[r] + bias;
    }
  }
  __syncthreads();

  // ---- Head: h1+BN. wave handles 2 positions, lane = output channel j ----
  {
    const float* sSig = sX + 1024;
    float* sBn = sX + 2112;  // [16][65]
    const int j = lane;
    const int pA = wvAll * 2, pB = pA + 1;
    float a0 = b1[j], a1 = a0;
    const float* sg0 = sSig + pA * 68;
    const float* sg1 = sSig + pB * 68;
    for (int i = 0; i < 64; ++i) {
      float wt = w1[i * 64 + j];
      a0 = fmaf(sg0[i], wt, a0);
      a1 = fmaf(sg1[i], wt, a1);
    }
#pragma unroll
    for (int i = 0; i < 5; ++i) {
      float wt = w1[(64 + i) * 64 + j];
      a0 = fmaf(sFeat[pA * 5 + i], wt, a0);
      a1 = fmaf(sFeat[pB * 5 + i], wt, a1);
    }
    float sc = gam[j] * rsqrtf(rvar[j] + 1e-5f);
    float rm = rmean[j], be = bet[j];
    sBn[pA * 65 + j] = fmaf(fmaxf(a0, 0.f) - rm, sc, be);
    sBn[pB * 65 + j] = fmaf(fmaxf(a1, 0.f) - rm, sc, be);
  }
  __syncthreads();

  // ---- h2 + output: 512 tasks = 16 pos x 32 k ----
  {
    const float* sBn = sX + 2112;
    const float b3s = b3[0];
    int p = tid >> 5, k = tid & 31;
    const float* bnp = sBn + p * 65;
    float a = b2[k];
    for (int jj = 0; jj < 64; ++jj) a = fmaf(bnp[jj], w2[jj * 32 + k], a);
    float partial = fmaxf(a, 0.f) * w3[k];
#pragma unroll
    for (int off = 16; off >= 1; off >>= 1) partial += __shfl_xor(partial, off, 32);
    if (k == 0) out[posBase + p] = 1.5f * tanhf(partial + b3s);
  }
}

extern "C" void kernel_launch(void* const* d_in, const int* in_sizes, int n_in,
                              void* d_out, int out_size, void* d_ws, size_t ws_size,
                              hipStream_t stream) {
  const float* F = (const float*)d_in[0];
  const float* hw1 = (const float*)d_in[1];
  const float* hb1 = (const float*)d_in[2];
  const float* hw2 = (const float*)d_in[3];
  const float* hb2 = (const float*)d_in[4];
  const float* hw3 = (const float*)d_in[5];
  const float* hb3 = (const float*)d_in[6];
  const float* gw1 = (const float*)d_in[7];
  const float* gb1 = (const float*)d_in[8];
  const float* gw2 = (const float*)d_in[9];
  const float* gb2 = (const float*)d_in[10];
  const float* p1 = (const float*)d_in[11];
  const float* p1b = (const float*)d_in[12];
  const float* p2 = (const float*)d_in[13];
  const float* p2b = (const float*)d_in[14];
  const float* p3 = (const float*)d_in[15];
  const float* p3b = (const float*)d_in[16];
  const float* p4 = (const float*)d_in[17];
  const float* p4b = (const float*)d_in[18];
  const float* w1 = (const float*)d_in[19];
  const float* b1 = (const float*)d_in[20];
  const float* gam = (const float*)d_in[21];
  const float* bet = (const float*)d_in[22];
  const float* rmean = (const float*)d_in[23];
  const float* rvar = (const float*)d_in[24];
  const float* w2 = (const float*)d_in[25];
  const float* b2 = (const float*)d_in[26];
  const float* w3 = (const float*)d_in[27];
  const float* b3 = (const float*)d_in[28];

  float* ws = (float*)d_ws;
  float* gate = ws;                                      // 262144 floats
  unsigned short* WtH = (unsigned short*)(ws + 262144);  // 65536 ushorts
  unsigned short* WtL = WtH + 65536;                     // 65536 ushorts
  float* out = (float*)d_out;                            // 65536 floats

  pre_kernel<<<512, 256, 0, stream>>>(F, hw1, hb1, hw2, hb2, hw3, hb3, gw1,
                                      gb1, gw2, gb2, p1, p2, p3, p4, WtH, WtL,
                                      gate);
  sig_kernel<<<4096, 512, 0, stream>>>(F, gate, WtH, WtL, p1b, p2b, p3b, p4b,
                                       w1, b1, gam, bet, rmean, rvar, w2, b2,
                                       w3, b3, out);
}